// Round 12
// baseline (160.399 us; speedup 1.0000x reference)
//
#include <hip/hip_runtime.h>
#include <hip/hip_bf16.h>

#define BB   8
#define SCTX 4096
#define SQ   512
#define EE   300
#define HH   128
#define EP   320    // E padded to multiple of 32
#define CST  328    // staged fp32->bf16 E-row stride (shorts)
#define LOG2E 1.4426950408889634f

// HIP predefines short4/float4/uint4 (hip_vector_types.h) — never shadow them.
typedef short bhalf4 __attribute__((ext_vector_type(4)));
typedef short short8 __attribute__((ext_vector_type(8)));
typedef float f32x4  __attribute__((ext_vector_type(4)));
typedef unsigned u32x4 __attribute__((ext_vector_type(4)));

#define MFMA16(a, b, c) __builtin_amdgcn_mfma_f32_16x16x32_bf16((a), (b), (c), 0, 0, 0)

__device__ __forceinline__ short f2bf(float f) {
  unsigned u = __builtin_bit_cast(unsigned, f);
  u += 0x7fffu + ((u >> 16) & 1u);
  return (short)(u >> 16);
}
__device__ __forceinline__ float bf2f(short s) {
  return __builtin_bit_cast(float, ((unsigned)(unsigned short)s) << 16);
}
__device__ __forceinline__ unsigned pack2(float a, float b) {
  return (unsigned)(unsigned short)f2bf(a) | ((unsigned)(unsigned short)f2bf(b) << 16);
}
// global -> LDS direct DMA, 16 B/lane. LDS dest = wave-uniform base + lane*16 (m104);
// global source is per-lane (swizzle goes on the SOURCE, rule #21).
__device__ __forceinline__ void gload16(const void* g, void* lds) {
  __builtin_amdgcn_global_load_lds(
      (const __attribute__((address_space(1))) void*)g,
      (__attribute__((address_space(3))) void*)lds, 16, 0, 0);
}

// ---------------- kernel 0: W (fp32 [128][300]) -> bf16 fragment-swizzled wsw ---------
// wsw element for W[h][k]: m=h>>4, t=h&15, kk=k>>5, quad=(k>>3)&3, j=k&7
//   wsw[((kk*8 + m)*64 + quad*16 + t)*8 + j]
// -> a wave reading frag (kk, m) issues one fully-coalesced 64-lane x 16 B load.
__global__ void k_wpad(const float* __restrict__ W, short* __restrict__ wsw) {
  const int h = blockIdx.x, k = threadIdx.x;
  float v = (k < EE) ? W[h * EE + k] : 0.0f;
  const int m = h >> 4, t = h & 15, kk = k >> 5, quad = (k >> 3) & 3, j = k & 7;
  wsw[((kk * 8 + m) * 64 + quad * 16 + t) * 8 + j] = f2bf(v);
}

// ---------------- kernel 1: qst logits -> ql [b][q][h] + qlT [b][h][q] ---------------
// R21-verified (best): 256 blocks, dual-layout MFMA, wsw-coalesced W-frags, b64 stores.
//   acc1 = MFMA16(a, w8): lane(t,quad) r = QL[q=q0+quad*4+r][h=habs+t] -> qlT b64
//   acc2 = MFMA16(w8, a): lane(t,quad) r = QL[q=q0+t][h=habs+quad*4+r] -> ql  b64
__global__ __launch_bounds__(256) void k_qlog(const float* __restrict__ qst,
                                              const short* __restrict__ wsw,
                                              const float* __restrict__ bias,
                                              short* __restrict__ ql,
                                              short* __restrict__ qlT) {
  const int b = blockIdx.y;
  const int q0 = blockIdx.x * 16;
  const int tid = threadIdx.x;
  const int w = tid >> 6, l = tid & 63, t = l & 15, quad = l >> 4;

  __shared__ __align__(16) short cst[16 * CST];

  const float4* cbase = (const float4*)(qst + (size_t)(b * SQ + q0) * EE);
#pragma unroll
  for (int j = 0; j < 5; ++j) {
    int i4 = tid + j * 256;
    if (i4 < 1200) {
      float4 v = cbase[i4];
      int row = i4 / 75, c4 = i4 - row * 75;
      bhalf4 s4; s4[0] = f2bf(v.x); s4[1] = f2bf(v.y); s4[2] = f2bf(v.z); s4[3] = f2bf(v.w);
      *(bhalf4*)(cst + row * CST + c4 * 4) = s4;
    }
  }
  for (int i = tid; i < 160; i += 256) {
    int row = i / 10, c = (i - row * 10) * 2;
    *(int*)&cst[row * CST + 300 + c] = 0;
  }
  __syncthreads();

  f32x4 acc1[2] = {}, acc2[2] = {};
  const short* arow = cst + t * CST;
#pragma unroll
  for (int kk = 0; kk < 10; ++kk) {
    short8 a = *(const short8*)(arow + kk * 32 + quad * 8);
#pragma unroll
    for (int n = 0; n < 2; ++n) {
      const int m = w * 2 + n;
      short8 w8 = *(const short8*)(wsw + ((kk * 8 + m) * 64 + l) * 8);  // coalesced
      acc1[n] = MFMA16(a, w8, acc1[n]);   // q in quad-dim, h in t-dim  -> qlT
      acc2[n] = MFMA16(w8, a, acc2[n]);   // h in quad-dim, q in t-dim  -> ql
    }
  }
#pragma unroll
  for (int n = 0; n < 2; ++n) {
    const int habs = (w * 2 + n) * 16;
    const float bv1 = bias[habs + t];
    bhalf4 s1;
#pragma unroll
    for (int r = 0; r < 4; ++r) s1[r] = f2bf(fmaxf(acc1[n][r] + bv1, 0.0f));
    *(bhalf4*)&qlT[((size_t)b * HH + habs + t) * SQ + q0 + quad * 4] = s1;
    const float4 bv2 = *(const float4*)(bias + habs + quad * 4);
    bhalf4 s2;
    s2[0] = f2bf(fmaxf(acc2[n][0] + bv2.x, 0.0f));
    s2[1] = f2bf(fmaxf(acc2[n][1] + bv2.y, 0.0f));
    s2[2] = f2bf(fmaxf(acc2[n][2] + bv2.z, 0.0f));
    s2[3] = f2bf(fmaxf(acc2[n][3] + bv2.w, 0.0f));
    *(bhalf4*)&ql[((size_t)b * SQ + q0 + t) * HH + habs + quad * 4] = s2;
  }
}

// ---------------- kernel 2: fused ctx-logits + QK^T + softmax (no-max) + PV ------------
// grid (SCTX/64, B) = 512 blocks; 4 waves; wave w owns ctx rows m0+w*16..+15, full q.
//
// LEDGER: R11 global-B = latency collapse. R14 tr_b16 = wrong elem order. R15 reg dbuf =
//   scratch spills. R12/R16/R17 staging variants + ILP batching ~40us. R18 "occupancy"
//   test was CONFOUNDED (halved tile + duplicated phase-A; regressed). R19 counted
//   vmcnt = no change. R21 1-barrier/chunk = small win. Plateau diagnosis: MfmaUtil<10%,
//   VALUBusy<20%, HBM<15% -> ~75% of cycles idle = latency exposure at 2 waves/SIMD.
// R22 (this): CLEAN TLP test. Same 64-row tile, same phase-A, same 1-barrier loop;
//   chunks 64->32 q so LDS = 39,424 B -> 4 blocks/CU (163,840/39,424 = 4.15).
//   __launch_bounds__(256,4) caps VGPR at 128 (R19's fatter state measured exactly 128;
//   this state is ~half: sv[2], pk[4], sA/sB[4]). WRITE_SIZE is the spill tripwire.
//   vbuf rows are now 64 B -> swizzle (row&3)<<4 (within-row; 2-way bank aliasing,
//   free per m136). qbuf unchanged ((row&7)<<4). PV uses ONE pa fragment per chunk
//   (kk2==0 case of the verified R15/R21 mapping; n2-parity = hiq).
// Max-subtraction dropped (S_max ~16 << 88; -8 centering in maskh; R10-verified).
__global__ __launch_bounds__(256, 4) void k_attn(const float* __restrict__ ctx,
                                                 const short* __restrict__ wsw,
                                                 const float* __restrict__ bias,
                                                 const int* __restrict__ mask,
                                                 const short* __restrict__ ql,
                                                 const short* __restrict__ qlT,
                                                 float* __restrict__ out) {
  const int b = blockIdx.y;
  const int m0 = blockIdx.x * 64;
  const int tid = threadIdx.x;
  const int w = tid >> 6, l = tid & 63, t = l & 15, quad = l >> 4;
  const int g = w >> 1, hf = w & 1;

  __shared__ __align__(16) short uq[10496];  // cst [32][328] (20,992 B) | qb0,qb1 [32][128] (16 KB)
  __shared__ __align__(16) short uv[8704];   // clt [64][136] (17,408 B) | vb0,vb1 [128][32] (16 KB)
  __shared__ __align__(16) short maskh[SQ];  // bf16 mask+exp-centering offsets (1 KB)
  short* cst = uq;
  short* clt = uv;
  short* qb0 = uq;          short* qb1 = uq + 4096;
  short* vb0 = uv;          short* vb1 = uv + 4096;

  for (int i = tid; i < SQ; i += 256)
    maskh[i] = f2bf(mask[b * SQ + i] ? -8.0f : -1e30f);  // -8 = exp-centering offset

  // ---- phase A: ctx_logits tile [64][128], two 32-row halves (unchanged) ----
  for (int i = 0; i < 2; ++i) {
    const float4* cbase = (const float4*)(ctx + ((size_t)b * SCTX + m0 + i * 32) * EE);
#pragma unroll
    for (int j = 0; j < 10; ++j) {
      int i4 = tid + j * 256;
      if (i4 < 2400) {
        float4 v = cbase[i4];
        int row = i4 / 75, c4 = i4 - row * 75;
        bhalf4 s4; s4[0] = f2bf(v.x); s4[1] = f2bf(v.y); s4[2] = f2bf(v.z); s4[3] = f2bf(v.w);
        *(bhalf4*)(cst + row * CST + c4 * 4) = s4;
      }
    }
    for (int k = tid; k < 320; k += 256) {
      int row = k / 10, c = (k - row * 10) * 2;
      *(int*)&cst[row * CST + 300 + c] = 0;
    }
    __syncthreads();
    const short* arow = cst + (g * 16 + t) * CST;
    f32x4 acc[4] = {};
#pragma unroll
    for (int kk = 0; kk < 10; ++kk) {
      const int k = kk * 32 + quad * 8;
      short8 a = *(const short8*)(arow + k);
      short8 w8[4];
#pragma unroll
      for (int n = 0; n < 4; ++n)
        w8[n] = *(const short8*)(wsw + ((kk * 8 + hf * 4 + n) * 64 + l) * 8);
#pragma unroll
      for (int n = 0; n < 4; ++n) acc[n] = MFMA16(a, w8[n], acc[n]);
    }
#pragma unroll
    for (int n = 0; n < 4; ++n) {
      const int h = (hf * 4 + n) * 16 + t;
      const float bv = bias[h];
#pragma unroll
      for (int r = 0; r < 4; ++r) {
        float v = fmaxf(acc[n][r] + bv, 0.0f);
        clt[(i * 32 + g * 16 + quad * 4 + r) * 136 + h] = f2bf(v);
      }
    }
    __syncthreads();  // clt written; cst free
  }

  // A-fragments for this wave's 16 ctx rows
  short8 af[4];
#pragma unroll
  for (int kk = 0; kk < 4; ++kk)
    af[kk] = *(const short8*)&clt[(w * 16 + t) * 136 + kk * 32 + quad * 8];
  __syncthreads();  // ALL waves' af (clt) reads drained before DMA overwrites uq/uv

  // ---- chunk machinery: 16 chunks x 32 q, double-buffered, 1 barrier/chunk ----
  const int srcA = ((quad & 1) * 2) * 16 + t;  // shfl source lanes for P-assembly
  const int srcB = srcA + 16;
  const bool hiq = quad >= 2;
  const int sxq = (t & 7) << 3;   // qbuf read-side XOR (shorts)
  const int sxv = (t & 3) << 3;   // vbuf read-side XOR (shorts; 64-B rows)
  const int rl4  = l >> 4;        // qbuf DMA: row-within-call (4 rows/call)
  const int cbq  = (l & 15) * 16; // qbuf DMA: linear col-byte in 256-B row
  const int rl16 = l >> 2;        // vbuf DMA: row-within-call (16 rows/call)
  const int cbv  = (l & 3) * 16;  // vbuf DMA: linear col-byte in 64-B row

  // 4 gload16/wave/chunk: Q 2 calls (4 rows each), V 2 calls (16 rows each).
  auto stageTo = [&](short* qb, short* vb, int c) {
#pragma unroll
    for (int s = 0; s < 2; ++s) {
      const int row = w * 8 + s * 4 + rl4;
      gload16((const char*)(ql + ((size_t)b * SQ + c * 32 + row) * HH) +
                  (cbq ^ ((row & 7) << 4)),
              qb + (w * 8 + s * 4) * 128);
    }
#pragma unroll
    for (int s = 0; s < 2; ++s) {
      const int row = w * 32 + s * 16 + rl16;
      gload16((const char*)(qlT + ((size_t)b * HH + row) * SQ + c * 32) +
                  (cbv ^ ((row & 3) << 4)),
              vb + (w * 32 + s * 16) * 32);
    }
  };

  stageTo(qb0, vb0, 0);  // drained at the first chunk barrier

  f32x4 o[8] = {};
  float rtot = 0.0f;
  for (int c = 0; c < 16; ++c) {
    short* qch = (c & 1) ? qb1 : qb0;
    short* vch = (c & 1) ? vb1 : vb0;
    // ONE barrier/chunk: drains chunk c's DMA (only outstanding vmem, issued a full
    // chunk ago) and orders all waves past chunk c-1's reads of the other buffer.
    __syncthreads();
    if (c < 15) stageTo((c & 1) ? qb0 : qb1, (c & 1) ? vb0 : vb1, c + 1);

    // ---- S: 8 MFMA (operand-swapped) ----
    f32x4 sv[2] = {};
#pragma unroll
    for (int n2 = 0; n2 < 2; ++n2) {
      const short* qr = qch + (n2 * 16 + t) * 128;
#pragma unroll
      for (int kx = 0; kx < 4; ++kx) {
        short8 b8 = *(const short8*)(qr + ((kx * 32 + quad * 8) ^ sxq));
        sv[n2] = MFMA16(b8, af[kx], sv[n2]);
      }
    }
    // ---- E: mask + exp + pack; lane(t,quad) r = P[q=c*32+n2*16+quad*4+r][ctx=t] ----
    unsigned pk[4];
#pragma unroll
    for (int n2 = 0; n2 < 2; ++n2) {
      bhalf4 mb = *(const bhalf4*)&maskh[c * 32 + n2 * 16 + quad * 4];
      float p0 = exp2f((sv[n2][0] + bf2f(mb[0])) * LOG2E);
      float p1 = exp2f((sv[n2][1] + bf2f(mb[1])) * LOG2E);
      float p2 = exp2f((sv[n2][2] + bf2f(mb[2])) * LOG2E);
      float p3 = exp2f((sv[n2][3] + bf2f(mb[3])) * LOG2E);
      rtot += (p0 + p1) + (p2 + p3);
      pk[n2 * 2 + 0] = pack2(p0, p1);
      pk[n2 * 2 + 1] = pack2(p2, p3);
    }
    // ---- X: 8 shuffles ----
    unsigned sA[4], sB[4];
#pragma unroll
    for (int i = 0; i < 4; ++i) {
      sA[i] = (unsigned)__shfl((int)pk[i], srcA);
      sB[i] = (unsigned)__shfl((int)pk[i], srcB);
    }
    // ---- PV: 8 MFMA (single 32-q block; verified mapping, n2-parity = hiq) ----
    u32x4 av;
    av[0] = hiq ? sA[2] : sA[0];
    av[1] = hiq ? sA[3] : sA[1];
    av[2] = hiq ? sB[2] : sB[0];
    av[3] = hiq ? sB[3] : sB[1];
    short8 pa = __builtin_bit_cast(short8, av);
#pragma unroll
    for (int n = 0; n < 8; ++n) {
      short8 v8 = *(const short8*)&vch[(n * 16 + t) * 32 + ((quad * 8) ^ sxv)];
      o[n] = MFMA16(pa, v8, o[n]);
    }
  }

  // ---- epilogue (register/shuffle only) ----
  rtot += __shfl_xor(rtot, 16);
  rtot += __shfl_xor(rtot, 32);  // lane x holds full denom for ctx row (x&15)
  f32x4 rinv;
#pragma unroll
  for (int r = 0; r < 4; ++r) rinv[r] = 1.0f / __shfl(rtot, quad * 4 + r);
  float* obase = out + ((size_t)b * SCTX + m0 + w * 16) * HH;
#pragma unroll
  for (int n = 0; n < 8; ++n)
#pragma unroll
    for (int r = 0; r < 4; ++r)
      obase[(quad * 4 + r) * HH + n * 16 + t] = o[n][r] * rinv[r];
}

extern "C" void kernel_launch(void* const* d_in, const int* in_sizes, int n_in,
                              void* d_out, int out_size, void* d_ws, size_t ws_size,
                              hipStream_t stream) {
  const float* ctx  = (const float*)d_in[0];
  const float* qst  = (const float*)d_in[1];
  const int*   mask = (const int*)d_in[2];
  const float* W    = (const float*)d_in[3];
  const float* bias = (const float*)d_in[4];
  float* out = (float*)d_out;

  // ws: wsw 80 KiB | ql 1 MiB | qlT 1 MiB
  short* wsw  = (short*)d_ws;
  short* ql   = (short*)((char*)d_ws + 81920);
  short* qlT  = ql + (size_t)BB * SQ * HH;

  k_wpad<<<dim3(HH), dim3(EP), 0, stream>>>(W, wsw);
  k_qlog<<<dim3(SQ / 16, BB), dim3(256), 0, stream>>>(qst, wsw, bias, ql, qlT);
  k_attn<<<dim3(SCTX / 64, BB), dim3(256), 0, stream>>>(ctx, wsw, bias, mask, ql, qlT, out);
}